// Round 4
// baseline (177.613 us; speedup 1.0000x reference)
//
#include <hip/hip_runtime.h>
#include <cstdint>

// AttentionFlow — fused MFMA, barrier-minimal version.
// B=8, T=2048, I=512, D=512. Output (B,T,4D) fp32.
//
//  1. prep_q:     sq[b,i] = <q,w_q>+b_q ; qb = bf16(q) [i-major]     (ws)
//  2. prep_qT:    qT = bf16(q^T) [d-major]                           (ws)
//  3. fused_attn: per 32-row t-tile (512 thr, 8 waves = 2m x 4n):
//                 phase1: S = (c.*w_cq)@q^T via direct-global frags (0 barriers)
//                 sc rowdot folded into A loads; exact softmax in regs;
//                 P->LDS bf16 (1 barrier); phase2: O = P@qT direct-global B
//                 (0 barriers); epilogue writes [c | c2q | c*c2q | -]
//  4. t_softmax:  bw = softmax_t(mrow)
//  5. q2c:        q2c[b,d] = sum_t bw*c (split-K 32)
//  6. slot3:      out[...,3D:4D] = c*q2c

constexpr int kB = 8;
constexpr int kT = 2048;
constexpr int kI = 512;
constexpr int kD = 512;
constexpr int kW = 4 * kD;

constexpr int kSplit = 32;
constexpr int kTchunk = kT / kSplit;  // 64

using f32x4  = __attribute__((ext_vector_type(4))) float;
using bf16x8 = __attribute__((ext_vector_type(8))) __bf16;

__device__ __forceinline__ float wave_max(float v) {
#pragma unroll
  for (int off = 32; off > 0; off >>= 1) v = fmaxf(v, __shfl_xor(v, off, 64));
  return v;
}
__device__ __forceinline__ float wave_sum(float v) {
#pragma unroll
  for (int off = 32; off > 0; off >>= 1) v += __shfl_xor(v, off, 64);
  return v;
}

// sq rowdot + q -> bf16 (i-major). One wave per row.
__global__ __launch_bounds__(256) void prep_q_kernel(
    const float* __restrict__ q, const float* __restrict__ w_q,
    const float* __restrict__ b_q, float* __restrict__ sq,
    __bf16* __restrict__ qb) {
  const int wave = (blockIdx.x * 256 + threadIdx.x) >> 6;
  const int lane = threadIdx.x & 63;
  const float* row = q + (size_t)wave * kD;
  __bf16* orow = qb + (size_t)wave * kD;
  float s = 0.f;
#pragma unroll
  for (int j = 0; j < kD / 64; ++j) {
    const float v = row[lane + j * 64];
    orow[lane + j * 64] = (__bf16)v;
    s += v * w_q[lane + j * 64];
  }
  s = wave_sum(s);
  if (lane == 0) sq[wave] = s + b_q[0];
}

// qT[b,d,i] = bf16(q[b,i,d]) via LDS transpose of 64x64 tiles
__global__ __launch_bounds__(256) void prep_qT_kernel(
    const float* __restrict__ q, __bf16* __restrict__ qT) {
  __shared__ float ts[64][68];
  const int b = blockIdx.z;
  const int i0 = blockIdx.x * 64;
  const int d0 = blockIdx.y * 64;
  const int tid = threadIdx.x;
  const int r = tid >> 2;         // 0..63
  const int cg = (tid & 3) * 16;  // 0,16,32,48
#pragma unroll
  for (int j = 0; j < 4; ++j) {
    f32x4 v = *(const f32x4*)(q + ((size_t)(b * kI + i0 + r)) * kD + d0 + cg + 4 * j);
    ts[r][cg + 4 * j + 0] = v.x;
    ts[r][cg + 4 * j + 1] = v.y;
    ts[r][cg + 4 * j + 2] = v.z;
    ts[r][cg + 4 * j + 3] = v.w;
  }
  __syncthreads();
  const int dl = tid >> 2;
  const int ig = (tid & 3) * 16;
  bf16x8 o0, o1;
#pragma unroll
  for (int j = 0; j < 8; ++j) o0[j] = (__bf16)ts[ig + j][dl];
#pragma unroll
  for (int j = 0; j < 8; ++j) o1[j] = (__bf16)ts[ig + 8 + j][dl];
  __bf16* dst = qT + ((size_t)(b * kD + d0 + dl)) * kI + i0 + ig;
  *(bf16x8*)dst = o0;
  *(bf16x8*)(dst + 8) = o1;
}

__global__ __launch_bounds__(512, 4) void fused_attn(
    const float* __restrict__ c, const __bf16* __restrict__ qb,
    const __bf16* __restrict__ qTb, const float* __restrict__ w_cq,
    const float* __restrict__ w_c, const float* __restrict__ b_c,
    const float* __restrict__ b_cq, const float* __restrict__ sq,
    float* __restrict__ out, float* __restrict__ mrow) {
  // lP: 16 k-chunks x 32 rows x 72B (32 bf16 + 8B pad)
  __shared__ __align__(16) char lP[16 * 2304];
  __shared__ float scrow[32];
  __shared__ float red[128];

  const int b = blockIdx.y;
  const int t0 = blockIdx.x * 32;
  const int tid = threadIdx.x;
  const int lane = tid & 63;
  const int w = tid >> 6;
  const int wm = w >> 2, wn = w & 3;   // wm: row-half, wn: 128-col slice
  const int lr = lane & 15, lg = lane >> 4;

  const float* cA = c + ((size_t)(b * kT + t0 + wm * 16 + lr)) * kD;
  const __bf16* qB = qb + ((size_t)(b * kI + wn * 128 + lr)) * kD;

  // ---------------- Phase 1: S = (c.*w_cq) @ q^T  (no barriers) ----------
  f32x4 acc[8] = {};
  float scp = 0.f;
  for (int k0 = 0; k0 < kD; k0 += 32) {
    const int ka = k0 + lg * 8;
    f32x4 a0 = *(const f32x4*)(cA + ka);
    f32x4 a1 = *(const f32x4*)(cA + ka + 4);
    const f32x4 w0 = *(const f32x4*)(w_cq + ka);
    const f32x4 w1 = *(const f32x4*)(w_cq + ka + 4);
    if (wn == 0) {
      const f32x4 u0 = *(const f32x4*)(w_c + ka);
      const f32x4 u1 = *(const f32x4*)(w_c + ka + 4);
      scp += a0.x * u0.x + a0.y * u0.y + a0.z * u0.z + a0.w * u0.w +
             a1.x * u1.x + a1.y * u1.y + a1.z * u1.z + a1.w * u1.w;
    }
    a0 *= w0;
    a1 *= w1;
    const bf16x8 af = {(__bf16)a0.x, (__bf16)a0.y, (__bf16)a0.z, (__bf16)a0.w,
                       (__bf16)a1.x, (__bf16)a1.y, (__bf16)a1.z, (__bf16)a1.w};
#pragma unroll
    for (int h = 0; h < 2; ++h) {
      bf16x8 bf_[4];
#pragma unroll
      for (int n4 = 0; n4 < 4; ++n4)
        bf_[n4] = *(const bf16x8*)(qB + (size_t)((h * 4 + n4) * 16) * kD + ka);
#pragma unroll
      for (int n4 = 0; n4 < 4; ++n4)
        acc[h * 4 + n4] = __builtin_amdgcn_mfma_f32_16x16x32_bf16(
            af, bf_[n4], acc[h * 4 + n4], 0, 0, 0);
    }
  }

  // sc rowdot finish (wn==0 waves hold rows wm*16+lr)
  if (wn == 0) {
    scp += __shfl_xor(scp, 16, 64);
    scp += __shfl_xor(scp, 32, 64);
    if (lg == 0) scrow[wm * 16 + lr] = scp + b_c[0];
  }
  __syncthreads();

  // biases
  const float bq = b_cq[0];
  float sqv[8];
#pragma unroll
  for (int n = 0; n < 8; ++n) sqv[n] = sq[b * kI + wn * 128 + n * 16 + lr];
  float scr[4];
#pragma unroll
  for (int r = 0; r < 4; ++r) scr[r] = scrow[wm * 16 + lg * 4 + r] + bq;
#pragma unroll
  for (int n = 0; n < 8; ++n)
#pragma unroll
    for (int r = 0; r < 4; ++r) acc[n][r] += scr[r] + sqv[n];

  // ---------------- exact softmax over i (512) ---------------------------
  float mx[4];
#pragma unroll
  for (int r = 0; r < 4; ++r) {
    float v = acc[0][r];
#pragma unroll
    for (int n = 1; n < 8; ++n) v = fmaxf(v, acc[n][r]);
#pragma unroll
    for (int off = 1; off <= 8; off <<= 1) v = fmaxf(v, __shfl_xor(v, off, 64));
    mx[r] = v;
  }
  if (lr == 0) {
#pragma unroll
    for (int r = 0; r < 4; ++r) red[wn * 32 + wm * 16 + lg * 4 + r] = mx[r];
  }
  __syncthreads();
#pragma unroll
  for (int r = 0; r < 4; ++r) {
    const int rw = wm * 16 + lg * 4 + r;
    mx[r] = fmaxf(fmaxf(red[rw], red[32 + rw]), fmaxf(red[64 + rw], red[96 + rw]));
  }
  if (wn == 0 && lr == 0) {
#pragma unroll
    for (int r = 0; r < 4; ++r)
      mrow[b * kT + t0 + wm * 16 + lg * 4 + r] = mx[r];
  }

  float sm[4] = {};
#pragma unroll
  for (int n = 0; n < 8; ++n)
#pragma unroll
    for (int r = 0; r < 4; ++r) {
      const float p = __expf(acc[n][r] - mx[r]);
      acc[n][r] = p;
      sm[r] += p;
    }
#pragma unroll
  for (int r = 0; r < 4; ++r)
#pragma unroll
    for (int off = 1; off <= 8; off <<= 1) sm[r] += __shfl_xor(sm[r], off, 64);
  __syncthreads();  // red reuse guard
  if (lr == 0) {
#pragma unroll
    for (int r = 0; r < 4; ++r) red[wn * 32 + wm * 16 + lg * 4 + r] = sm[r];
  }
  __syncthreads();
  float inv[4];
#pragma unroll
  for (int r = 0; r < 4; ++r) {
    const int rw = wm * 16 + lg * 4 + r;
    inv[r] = 1.f / (red[rw] + red[32 + rw] + red[64 + rw] + red[96 + rw]);
  }

  // ---------------- P (bf16) -> lP, k-chunked ----------------------------
#pragma unroll
  for (int r = 0; r < 4; ++r) {
    const int trow = wm * 16 + lg * 4 + r;
#pragma unroll
    for (int n = 0; n < 8; ++n) {
      const int icol = wn * 128 + n * 16 + lr;
      const int kk = icol >> 5, kc = icol & 31;
      *(__bf16*)(lP + kk * 2304 + trow * 72 + kc * 2) =
          (__bf16)(acc[n][r] * inv[r]);
    }
  }
  __syncthreads();

  // ---------------- Phase 2: O = P @ q  (no barriers) --------------------
  f32x4 o[8] = {};
  const __bf16* qT = qTb + ((size_t)(b * kD + wn * 128 + lr)) * kI;
  for (int k0 = 0; k0 < kI; k0 += 32) {
    const bf16x8 af2 =
        *(const bf16x8*)(lP + (k0 >> 5) * 2304 + (wm * 16 + lr) * 72 + lg * 16);
    const int ka = k0 + lg * 8;
#pragma unroll
    for (int h = 0; h < 2; ++h) {
      bf16x8 bf_[4];
#pragma unroll
      for (int n4 = 0; n4 < 4; ++n4)
        bf_[n4] = *(const bf16x8*)(qT + (size_t)((h * 4 + n4) * 16) * kI + ka);
#pragma unroll
      for (int n4 = 0; n4 < 4; ++n4)
        o[h * 4 + n4] = __builtin_amdgcn_mfma_f32_16x16x32_bf16(
            af2, bf_[n4], o[h * 4 + n4], 0, 0, 0);
    }
  }

  // ---------------- epilogue: slots [c | c2q | c*c2q] --------------------
#pragma unroll
  for (int r = 0; r < 4; ++r) {
    const int t = t0 + wm * 16 + lg * 4 + r;
    const size_t rb = (size_t)(b * kT + t);
    const float* crow = c + rb * kD;
    float* orow = out + rb * kW;
#pragma unroll
    for (int n = 0; n < 8; ++n) {
      const int d = wn * 128 + n * 16 + lr;
      const float cvv = crow[d];
      const float pv = o[n][r];
      orow[d] = cvv;
      orow[kD + d] = pv;
      orow[2 * kD + d] = cvv * pv;
    }
  }
}

__global__ __launch_bounds__(1024) void t_softmax_kernel(
    const float* __restrict__ mrow, float* __restrict__ bw) {
  const int b = blockIdx.x;
  const int tid = threadIdx.x;
  const float v0 = mrow[b * kT + tid], v1 = mrow[b * kT + tid + 1024];
  __shared__ float redm[16];
  __shared__ float reds[16];
  const int wave = tid >> 6, lane = tid & 63;
  float mx = wave_max(fmaxf(v0, v1));
  if (lane == 0) redm[wave] = mx;
  __syncthreads();
  mx = redm[0];
#pragma unroll
  for (int i = 1; i < 16; ++i) mx = fmaxf(mx, redm[i]);
  const float e0 = __expf(v0 - mx), e1 = __expf(v1 - mx);
  float sm = wave_sum(e0 + e1);
  if (lane == 0) reds[wave] = sm;
  __syncthreads();
  sm = 0.f;
#pragma unroll
  for (int i = 0; i < 16; ++i) sm += reds[i];
  const float inv = 1.f / sm;
  bw[b * kT + tid] = e0 * inv;
  bw[b * kT + tid + 1024] = e1 * inv;
}

__global__ __launch_bounds__(256) void q2c_part_kernel(
    const float* __restrict__ c, const float* __restrict__ bw,
    float* __restrict__ part) {
  const int b = blockIdx.y;
  const int sp = blockIdx.x;
  const int tid = threadIdx.x;
  const int d0 = tid, d1 = tid + 256;
  float a0 = 0.f, a1 = 0.f;
  const int tbase = sp * kTchunk;
  for (int t = 0; t < kTchunk; ++t) {
    const float w = bw[b * kT + tbase + t];
    const float* crow = c + ((size_t)b * kT + tbase + t) * kD;
    a0 += w * crow[d0];
    a1 += w * crow[d1];
  }
  part[((size_t)b * kSplit + sp) * kD + d0] = a0;
  part[((size_t)b * kSplit + sp) * kD + d1] = a1;
}

__global__ __launch_bounds__(512) void q2c_reduce_kernel(
    const float* __restrict__ part, float* __restrict__ q2c) {
  const int b = blockIdx.x;
  const int d = threadIdx.x;
  float s = 0.f;
#pragma unroll
  for (int p = 0; p < kSplit; ++p) s += part[((size_t)b * kSplit + p) * kD + d];
  q2c[b * kD + d] = s;
}

__global__ __launch_bounds__(128) void slot3_kernel(
    const float* __restrict__ c, const float* __restrict__ q2c,
    float* __restrict__ out) {
  const int row = blockIdx.x;  // b*kT + t
  const int b = row >> 11;
  const int x4 = threadIdx.x * 4;
  f32x4 cv = *(const f32x4*)(c + (size_t)row * kD + x4);
  f32x4 qc = *(const f32x4*)(q2c + b * kD + x4);
  *(f32x4*)(out + (size_t)row * kW + 3 * kD + x4) = cv * qc;
}

extern "C" void kernel_launch(void* const* d_in, const int* in_sizes, int n_in,
                              void* d_out, int out_size, void* d_ws, size_t ws_size,
                              hipStream_t stream) {
  const float* c    = (const float*)d_in[0];
  const float* q    = (const float*)d_in[1];
  const float* w_c  = (const float*)d_in[2];
  const float* b_c  = (const float*)d_in[3];
  const float* w_q  = (const float*)d_in[4];
  const float* b_q  = (const float*)d_in[5];
  const float* w_cq = (const float*)d_in[6];
  const float* b_cq = (const float*)d_in[7];
  float* out = (float*)d_out;
  float* ws = (float*)d_ws;

  // ws layout (floats): sq 4096 | mrow 16384 | bw 16384 | part 131072 |
  //                     q2c 4096  -> 171. Then bf16: qb 2M | qT 2M (~8.9MB tot)
  float* sq   = ws;
  float* mrow = sq + kB * kI;
  float* bw   = mrow + kB * kT;
  float* part = bw + kB * kT;
  float* q2c  = part + (size_t)kB * kSplit * kD;
  __bf16* qb = (__bf16*)(q2c + kB * kD);
  __bf16* qT = qb + (size_t)kB * kI * kD;

  prep_q_kernel<<<kB * kI / 4, 256, 0, stream>>>(q, w_q, b_q, sq, qb);
  dim3 gt(kI / 64, kD / 64, kB);
  prep_qT_kernel<<<gt, 256, 0, stream>>>(q, qT);

  dim3 gf(kT / 32, kB);
  fused_attn<<<gf, 512, 0, stream>>>(c, qb, qT, w_cq, w_c, b_c, b_cq, sq, out,
                                     mrow);

  t_softmax_kernel<<<kB, 1024, 0, stream>>>(mrow, bw);
  dim3 gq(kSplit, kB);
  q2c_part_kernel<<<gq, 256, 0, stream>>>(c, bw, part);
  q2c_reduce_kernel<<<kB, 512, 0, stream>>>(part, q2c);

  slot3_kernel<<<kB * kT, 128, 0, stream>>>(c, q2c, out);
}

// Round 5
// 103.795 us; speedup vs baseline: 1.7112x; 1.7112x over previous
//
#include <hip/hip_runtime.h>
#include <cstdint>

// AttentionFlow — fused MFMA with fragment-major packed q.
// B=8, T=2048, I=512, D=512. Output (B,T,4D) fp32.
//
//  1. prep_qf: qf = bf16 q packed in MFMA-B fragment order (phase-1),
//              + sq rowdot folded in                              (ws)
//  2. prep_vf: vf = bf16 q^T packed in MFMA-B fragment order (phase-2) (ws)
//  3. fused_attn: 32-row t-tile, 8 waves x 64-col slices:
//     phase1 S=(c.*w_cq)@q^T (0 barriers, coalesced L2 frag loads),
//     exact softmax in regs, P->LDS, phase2 O=P@qT (0 barriers),
//     epilogue [c | c2q | c*c2q | -]; mrow -> ws
//  4. t_softmax; 5. q2c split-K; 6. slot3 = c*q2c

constexpr int kB = 8;
constexpr int kT = 2048;
constexpr int kI = 512;
constexpr int kD = 512;
constexpr int kW = 4 * kD;

constexpr int kSplit = 32;
constexpr int kTchunk = kT / kSplit;  // 64

using f32x4  = __attribute__((ext_vector_type(4))) float;
using bf16x8 = __attribute__((ext_vector_type(8))) __bf16;

__device__ __forceinline__ float wave_max(float v) {
#pragma unroll
  for (int off = 32; off > 0; off >>= 1) v = fmaxf(v, __shfl_xor(v, off, 64));
  return v;
}
__device__ __forceinline__ float wave_sum(float v) {
#pragma unroll
  for (int off = 32; off > 0; off >>= 1) v += __shfl_xor(v, off, 64);
  return v;
}
__device__ __forceinline__ float dot8(const f32x4& a0, const f32x4& a1,
                                      const f32x4& b0, const f32x4& b1) {
  return a0.x * b0.x + a0.y * b0.y + a0.z * b0.z + a0.w * b0.w +
         a1.x * b1.x + a1.y * b1.y + a1.z * b1.z + a1.w * b1.w;
}

// qf[((b*32+g)*16+kk)*512 + lane*8 + j] = bf16(q[b][g*16+(lane&15)]
//                                               [kk*32+(lane>>4)*8+j])
// + sq[b,i] = <q,w_q>+b_q
__global__ __launch_bounds__(256) void prep_qf_kernel(
    const float* __restrict__ q, const float* __restrict__ w_q,
    const float* __restrict__ b_q, float* __restrict__ sq,
    __bf16* __restrict__ qf) {
  __shared__ float sacc[16][17];
  const int b = blockIdx.y;
  const int g = blockIdx.x;  // 0..31
  const int tid = threadIdx.x;
  const int kk0 = tid >> 6;
  const int lane = tid & 63;
  const int lr = lane & 15, lg = lane >> 4;
  const float* row = q + ((size_t)(b * kI + g * 16 + lr)) * kD;
  float sp = 0.f;
#pragma unroll
  for (int kk = kk0; kk < 16; kk += 4) {
    const int ka = kk * 32 + lg * 8;
    f32x4 v0 = *(const f32x4*)(row + ka);
    f32x4 v1 = *(const f32x4*)(row + ka + 4);
    f32x4 u0 = *(const f32x4*)(w_q + ka);
    f32x4 u1 = *(const f32x4*)(w_q + ka + 4);
    sp += dot8(v0, v1, u0, u1);
    bf16x8 o = {(__bf16)v0.x, (__bf16)v0.y, (__bf16)v0.z, (__bf16)v0.w,
                (__bf16)v1.x, (__bf16)v1.y, (__bf16)v1.z, (__bf16)v1.w};
    *(bf16x8*)(qf + ((((size_t)(b * 32 + g)) * 16 + kk) << 9) + lane * 8) = o;
  }
  sacc[lr][kk0 * 4 + lg] = sp;
  __syncthreads();
  if (tid < 16) {
    float s = 0.f;
#pragma unroll
    for (int j = 0; j < 16; ++j) s += sacc[tid][j];
    sq[b * kI + g * 16 + tid] = s + b_q[0];
  }
}

// vf[((b*32+gd)*16+kki)*512 + lane*8 + j] = bf16(q[b][kki*32+(lane>>4)*8+j]
//                                                 [gd*16+(lane&15)])
__global__ __launch_bounds__(256) void prep_vf_kernel(
    const float* __restrict__ q, __bf16* __restrict__ vf) {
  __shared__ float ts[64][68];
  const int b = blockIdx.z;
  const int i0 = blockIdx.x * 64;
  const int d0 = blockIdx.y * 64;
  const int tid = threadIdx.x;
  const int r = tid >> 2;
  const int cg = (tid & 3) * 16;
#pragma unroll
  for (int j = 0; j < 4; ++j) {
    f32x4 v = *(const f32x4*)(q + ((size_t)(b * kI + i0 + r)) * kD + d0 + cg + 4 * j);
    ts[r][cg + 4 * j + 0] = v.x;
    ts[r][cg + 4 * j + 1] = v.y;
    ts[r][cg + 4 * j + 2] = v.z;
    ts[r][cg + 4 * j + 3] = v.w;
  }
  __syncthreads();
  const int dl = tid >> 2;
  const int ig = (tid & 3) * 16;
  bf16x8 o0, o1;
#pragma unroll
  for (int j = 0; j < 8; ++j) o0[j] = (__bf16)ts[ig + j][dl];
#pragma unroll
  for (int j = 0; j < 8; ++j) o1[j] = (__bf16)ts[ig + 8 + j][dl];
  const int gd = (d0 >> 4) + (dl >> 4);
  const int lr = dl & 15;
  const int kki0 = (i0 >> 5) + (ig >> 5);
  const int lg0 = (ig & 31) >> 3;
  const int i1 = ig + 8;
  const int kki1 = (i0 >> 5) + (i1 >> 5);
  const int lg1 = (i1 & 31) >> 3;
  *(bf16x8*)(vf + ((((size_t)(b * 32 + gd)) * 16 + kki0) << 9) +
             (lg0 * 16 + lr) * 8) = o0;
  *(bf16x8*)(vf + ((((size_t)(b * 32 + gd)) * 16 + kki1) << 9) +
             (lg1 * 16 + lr) * 8) = o1;
}

__global__ __launch_bounds__(512, 4) void fused_attn(
    const float* __restrict__ c, const __bf16* __restrict__ qf,
    const __bf16* __restrict__ vf, const float* __restrict__ w_cq,
    const float* __restrict__ w_c, const float* __restrict__ b_c,
    const float* __restrict__ b_cq, const float* __restrict__ sq,
    float* __restrict__ out, float* __restrict__ mrow) {
  __shared__ __align__(16) char lP[16 * 2304];  // 16 k-chunks x 32 rows x 72B
  __shared__ float lwcq[512];
  __shared__ float lwc[512];
  __shared__ float scrow[32];
  __shared__ float redm[256];
  __shared__ float reds[256];

  const int b = blockIdx.y;
  const int t0 = blockIdx.x * 32;
  const int tid = threadIdx.x;
  const int w = tid >> 6;  // 0..7: 64-wide i (phase1) / d (phase2) slice
  const int lane = tid & 63;
  const int lr = lane & 15, lg = lane >> 4;

  lwcq[tid] = w_cq[tid];
  lwc[tid] = w_c[tid];
  __syncthreads();

  const float* cA0 = c + ((size_t)(b * kT + t0 + lr)) * kD;
  const float* cA1 = cA0 + (size_t)16 * kD;
  const __bf16* qfb = qf + (((size_t)(b * 32 + w * 4)) * 16 << 9);

  // ---------------- Phase 1: S = (c.*w_cq) @ q^T (0 barriers) ------------
  f32x4 acc[2][4] = {};
  float scp0 = 0.f, scp1 = 0.f;
  for (int kk = 0; kk < 16; ++kk) {
    const int ka = kk * 32 + lg * 8;
    f32x4 a00 = *(const f32x4*)(cA0 + ka);
    f32x4 a01 = *(const f32x4*)(cA0 + ka + 4);
    f32x4 a10 = *(const f32x4*)(cA1 + ka);
    f32x4 a11 = *(const f32x4*)(cA1 + ka + 4);
    const f32x4 w0 = *(const f32x4*)(lwcq + ka);
    const f32x4 w1 = *(const f32x4*)(lwcq + ka + 4);
    if (w == 0) {
      const f32x4 u0 = *(const f32x4*)(lwc + ka);
      const f32x4 u1 = *(const f32x4*)(lwc + ka + 4);
      scp0 += dot8(a00, a01, u0, u1);
      scp1 += dot8(a10, a11, u0, u1);
    }
    a00 *= w0;
    a01 *= w1;
    a10 *= w0;
    a11 *= w1;
    const bf16x8 af0 = {(__bf16)a00.x, (__bf16)a00.y, (__bf16)a00.z, (__bf16)a00.w,
                        (__bf16)a01.x, (__bf16)a01.y, (__bf16)a01.z, (__bf16)a01.w};
    const bf16x8 af1 = {(__bf16)a10.x, (__bf16)a10.y, (__bf16)a10.z, (__bf16)a10.w,
                        (__bf16)a11.x, (__bf16)a11.y, (__bf16)a11.z, (__bf16)a11.w};
    bf16x8 bfv[4];
#pragma unroll
    for (int n4 = 0; n4 < 4; ++n4)
      bfv[n4] = *(const bf16x8*)(qfb + (((size_t)(n4 * 16 + kk)) << 9) + lane * 8);
#pragma unroll
    for (int n4 = 0; n4 < 4; ++n4) {
      acc[0][n4] = __builtin_amdgcn_mfma_f32_16x16x32_bf16(af0, bfv[n4], acc[0][n4], 0, 0, 0);
      acc[1][n4] = __builtin_amdgcn_mfma_f32_16x16x32_bf16(af1, bfv[n4], acc[1][n4], 0, 0, 0);
    }
  }

  // sc rowdot finish (wave 0 holds rows lr and 16+lr)
  if (w == 0) {
    scp0 += __shfl_xor(scp0, 16, 64);
    scp0 += __shfl_xor(scp0, 32, 64);
    scp1 += __shfl_xor(scp1, 16, 64);
    scp1 += __shfl_xor(scp1, 32, 64);
    if (lg == 0) {
      scrow[lr] = scp0 + b_c[0];
      scrow[16 + lr] = scp1 + b_c[0];
    }
  }
  __syncthreads();

  // biases
  const float bq = b_cq[0];
  float sqv[4];
#pragma unroll
  for (int n4 = 0; n4 < 4; ++n4) sqv[n4] = sq[b * kI + w * 64 + n4 * 16 + lr];
  float scr[2][4];
#pragma unroll
  for (int m = 0; m < 2; ++m)
#pragma unroll
    for (int r = 0; r < 4; ++r) scr[m][r] = scrow[m * 16 + lg * 4 + r] + bq;
#pragma unroll
  for (int m = 0; m < 2; ++m)
#pragma unroll
    for (int n4 = 0; n4 < 4; ++n4)
#pragma unroll
      for (int r = 0; r < 4; ++r) acc[m][n4][r] += scr[m][r] + sqv[n4];

  // ---------------- exact softmax over i (512) ---------------------------
  float mx[2][4];
#pragma unroll
  for (int m = 0; m < 2; ++m)
#pragma unroll
    for (int r = 0; r < 4; ++r) {
      float v = acc[m][0][r];
#pragma unroll
      for (int n4 = 1; n4 < 4; ++n4) v = fmaxf(v, acc[m][n4][r]);
#pragma unroll
      for (int off = 1; off <= 8; off <<= 1) v = fmaxf(v, __shfl_xor(v, off, 64));
      mx[m][r] = v;
    }
  if (lr == 0) {
#pragma unroll
    for (int m = 0; m < 2; ++m)
#pragma unroll
      for (int r = 0; r < 4; ++r)
        redm[w * 32 + m * 16 + lg * 4 + r] = mx[m][r];
  }
  __syncthreads();
#pragma unroll
  for (int m = 0; m < 2; ++m)
#pragma unroll
    for (int r = 0; r < 4; ++r) {
      const int rw = m * 16 + lg * 4 + r;
      float v = redm[rw];
#pragma unroll
      for (int w2 = 1; w2 < 8; ++w2) v = fmaxf(v, redm[w2 * 32 + rw]);
      mx[m][r] = v;
    }
  if (w == 0 && lr == 0) {
#pragma unroll
    for (int m = 0; m < 2; ++m)
#pragma unroll
      for (int r = 0; r < 4; ++r)
        mrow[b * kT + t0 + m * 16 + lg * 4 + r] = mx[m][r];
  }

  float sm[2][4] = {};
#pragma unroll
  for (int m = 0; m < 2; ++m)
#pragma unroll
    for (int n4 = 0; n4 < 4; ++n4)
#pragma unroll
      for (int r = 0; r < 4; ++r) {
        const float p = __expf(acc[m][n4][r] - mx[m][r]);
        acc[m][n4][r] = p;
        sm[m][r] += p;
      }
#pragma unroll
  for (int m = 0; m < 2; ++m)
#pragma unroll
    for (int r = 0; r < 4; ++r)
#pragma unroll
      for (int off = 1; off <= 8; off <<= 1)
        sm[m][r] += __shfl_xor(sm[m][r], off, 64);
  if (lr == 0) {
#pragma unroll
    for (int m = 0; m < 2; ++m)
#pragma unroll
      for (int r = 0; r < 4; ++r)
        reds[w * 32 + m * 16 + lg * 4 + r] = sm[m][r];
  }
  __syncthreads();
  float inv[2][4];
#pragma unroll
  for (int m = 0; m < 2; ++m)
#pragma unroll
    for (int r = 0; r < 4; ++r) {
      const int rw = m * 16 + lg * 4 + r;
      float v = reds[rw];
#pragma unroll
      for (int w2 = 1; w2 < 8; ++w2) v += reds[w2 * 32 + rw];
      inv[m][r] = 1.f / v;
    }

  // ---------------- P (bf16) -> lP, k-chunked ----------------------------
#pragma unroll
  for (int m = 0; m < 2; ++m)
#pragma unroll
    for (int r = 0; r < 4; ++r) {
      const int trow = m * 16 + lg * 4 + r;
#pragma unroll
      for (int n4 = 0; n4 < 4; ++n4) {
        const int icol = w * 64 + n4 * 16 + lr;
        const int kkc = icol >> 5, kc = icol & 31;
        *(__bf16*)(lP + kkc * 2304 + trow * 72 + kc * 2) =
            (__bf16)(acc[m][n4][r] * inv[m][r]);
      }
    }
  __syncthreads();

  // ---------------- Phase 2: O = P @ q (0 barriers) ----------------------
  f32x4 o[2][4] = {};
  const __bf16* vfb = vf + (((size_t)(b * 32 + w * 4)) * 16 << 9);
  for (int kki = 0; kki < 16; ++kki) {
    const bf16x8 a0 = *(const bf16x8*)(lP + kki * 2304 + lr * 72 + lg * 16);
    const bf16x8 a1 = *(const bf16x8*)(lP + kki * 2304 + (16 + lr) * 72 + lg * 16);
    bf16x8 bfv[4];
#pragma unroll
    for (int n4 = 0; n4 < 4; ++n4)
      bfv[n4] = *(const bf16x8*)(vfb + (((size_t)(n4 * 16 + kki)) << 9) + lane * 8);
#pragma unroll
    for (int n4 = 0; n4 < 4; ++n4) {
      o[0][n4] = __builtin_amdgcn_mfma_f32_16x16x32_bf16(a0, bfv[n4], o[0][n4], 0, 0, 0);
      o[1][n4] = __builtin_amdgcn_mfma_f32_16x16x32_bf16(a1, bfv[n4], o[1][n4], 0, 0, 0);
    }
  }

  // ---------------- epilogue: slots [c | c2q | c*c2q] --------------------
#pragma unroll
  for (int m = 0; m < 2; ++m)
#pragma unroll
    for (int r = 0; r < 4; ++r) {
      const int t = t0 + m * 16 + lg * 4 + r;
      const size_t rb = (size_t)(b * kT + t);
      const float* crow = c + rb * kD;
      float* orow = out + rb * kW;
#pragma unroll
      for (int n4 = 0; n4 < 4; ++n4) {
        const int d = w * 64 + n4 * 16 + lr;
        const float cvv = crow[d];
        const float pv = o[m][n4][r];
        orow[d] = cvv;
        orow[kD + d] = pv;
        orow[2 * kD + d] = cvv * pv;
      }
    }
}

__global__ __launch_bounds__(1024) void t_softmax_kernel(
    const float* __restrict__ mrow, float* __restrict__ bw) {
  const int b = blockIdx.x;
  const int tid = threadIdx.x;
  const float v0 = mrow[b * kT + tid], v1 = mrow[b * kT + tid + 1024];
  __shared__ float redm[16];
  __shared__ float reds[16];
  const int wave = tid >> 6, lane = tid & 63;
  float mx = wave_max(fmaxf(v0, v1));
  if (lane == 0) redm[wave] = mx;
  __syncthreads();
  mx = redm[0];
#pragma unroll
  for (int i = 1; i < 16; ++i) mx = fmaxf(mx, redm[i]);
  const float e0 = __expf(v0 - mx), e1 = __expf(v1 - mx);
  float sm = wave_sum(e0 + e1);
  if (lane == 0) reds[wave] = sm;
  __syncthreads();
  sm = 0.f;
#pragma unroll
  for (int i = 0; i < 16; ++i) sm += reds[i];
  const float inv = 1.f / sm;
  bw[b * kT + tid] = e0 * inv;
  bw[b * kT + tid + 1024] = e1 * inv;
}

__global__ __launch_bounds__(256) void q2c_part_kernel(
    const float* __restrict__ c, const float* __restrict__ bw,
    float* __restrict__ part) {
  const int b = blockIdx.y;
  const int sp = blockIdx.x;
  const int tid = threadIdx.x;
  const int d0 = tid, d1 = tid + 256;
  float a0 = 0.f, a1 = 0.f;
  const int tbase = sp * kTchunk;
  for (int t = 0; t < kTchunk; ++t) {
    const float w = bw[b * kT + tbase + t];
    const float* crow = c + ((size_t)b * kT + tbase + t) * kD;
    a0 += w * crow[d0];
    a1 += w * crow[d1];
  }
  part[((size_t)b * kSplit + sp) * kD + d0] = a0;
  part[((size_t)b * kSplit + sp) * kD + d1] = a1;
}

__global__ __launch_bounds__(512) void q2c_reduce_kernel(
    const float* __restrict__ part, float* __restrict__ q2c) {
  const int b = blockIdx.x;
  const int d = threadIdx.x;
  float s = 0.f;
#pragma unroll
  for (int p = 0; p < kSplit; ++p) s += part[((size_t)b * kSplit + p) * kD + d];
  q2c[b * kD + d] = s;
}

__global__ __launch_bounds__(128) void slot3_kernel(
    const float* __restrict__ c, const float* __restrict__ q2c,
    float* __restrict__ out) {
  const int row = blockIdx.x;  // b*kT + t
  const int b = row >> 11;
  const int x4 = threadIdx.x * 4;
  f32x4 cv = *(const f32x4*)(c + (size_t)row * kD + x4);
  f32x4 qc = *(const f32x4*)(q2c + b * kD + x4);
  *(f32x4*)(out + (size_t)row * kW + 3 * kD + x4) = cv * qc;
}

extern "C" void kernel_launch(void* const* d_in, const int* in_sizes, int n_in,
                              void* d_out, int out_size, void* d_ws, size_t ws_size,
                              hipStream_t stream) {
  const float* c    = (const float*)d_in[0];
  const float* q    = (const float*)d_in[1];
  const float* w_c  = (const float*)d_in[2];
  const float* b_c  = (const float*)d_in[3];
  const float* w_q  = (const float*)d_in[4];
  const float* b_q  = (const float*)d_in[5];
  const float* w_cq = (const float*)d_in[6];
  const float* b_cq = (const float*)d_in[7];
  float* out = (float*)d_out;
  float* ws = (float*)d_ws;

  // ws layout (floats): sq 4096 | mrow 16384 | bw 16384 | part 131072 |
  //                     q2c 4096; then bf16: qf 2M | vf 2M  (~8.7 MB)
  float* sq   = ws;
  float* mrow = sq + kB * kI;
  float* bw   = mrow + kB * kT;
  float* part = bw + kB * kT;
  float* q2c  = part + (size_t)kB * kSplit * kD;
  __bf16* qf = (__bf16*)(q2c + kB * kD);
  __bf16* vf = qf + (size_t)kB * kI * kD;

  dim3 gpq(kI / 16, kB);
  prep_qf_kernel<<<gpq, 256, 0, stream>>>(q, w_q, b_q, sq, qf);
  dim3 gpv(kI / 64, kD / 64, kB);
  prep_vf_kernel<<<gpv, 256, 0, stream>>>(q, vf);

  dim3 gf(kT / 32, kB);
  fused_attn<<<gf, 512, 0, stream>>>(c, qf, vf, w_cq, w_c, b_c, b_cq, sq, out,
                                     mrow);

  t_softmax_kernel<<<kB, 1024, 0, stream>>>(mrow, bw);
  dim3 gq(kSplit, kB);
  q2c_part_kernel<<<gq, 256, 0, stream>>>(c, bw, part);
  q2c_reduce_kernel<<<kB, 512, 0, stream>>>(part, q2c);

  slot3_kernel<<<kB * kT, 128, 0, stream>>>(c, q2c, out);
}

// Round 6
// 81.641 us; speedup vs baseline: 2.1755x; 1.2714x over previous
//
#include <hip/hip_runtime.h>
#include <cstdint>

// AttentionFlow — fused MFMA; LDS-staged A, prefetched fragment-major B.
// B=8, T=2048, I=512, D=512. Output (B,T,4D) fp32.
//
//  1. prep_qf: qf = bf16 q packed in MFMA-B fragment order (phase-1) + sq
//  2. prep_vf: vf = bf16 q^T packed in MFMA-B fragment order (phase-2)
//  3. fused_attn: 32-row t-tile, 8 waves x 64-col slices:
//     stage A=bf16(c.*w_cq)->LDS once (sc rowdot folded in);
//     phase1 S=A@qf (LDS A + prefetched L2 B, 0 barriers);
//     exact softmax in regs; P->LDS (aliases A); phase2 O=P@vf
//     (prefetched); epilogue [c | c2q | c*c2q | -]; mrow -> ws
//  4. t_softmax; 5. q2c split-K; 6. slot3 = c*q2c

constexpr int kB = 8;
constexpr int kT = 2048;
constexpr int kI = 512;
constexpr int kD = 512;
constexpr int kW = 4 * kD;

constexpr int kSplit = 32;
constexpr int kTchunk = kT / kSplit;  // 64

using f32x4  = __attribute__((ext_vector_type(4))) float;
using bf16x4 = __attribute__((ext_vector_type(4))) __bf16;
using bf16x8 = __attribute__((ext_vector_type(8))) __bf16;

__device__ __forceinline__ float wave_max(float v) {
#pragma unroll
  for (int off = 32; off > 0; off >>= 1) v = fmaxf(v, __shfl_xor(v, off, 64));
  return v;
}
__device__ __forceinline__ float wave_sum(float v) {
#pragma unroll
  for (int off = 32; off > 0; off >>= 1) v += __shfl_xor(v, off, 64);
  return v;
}
__device__ __forceinline__ float dot8(const f32x4& a0, const f32x4& a1,
                                      const f32x4& b0, const f32x4& b1) {
  return a0.x * b0.x + a0.y * b0.y + a0.z * b0.z + a0.w * b0.w +
         a1.x * b1.x + a1.y * b1.y + a1.z * b1.z + a1.w * b1.w;
}

// qf[((b*32+g)*16+kk)*512 + lane*8 + j] = bf16(q[b][g*16+(lane&15)]
//                                               [kk*32+(lane>>4)*8+j])
__global__ __launch_bounds__(256) void prep_qf_kernel(
    const float* __restrict__ q, const float* __restrict__ w_q,
    const float* __restrict__ b_q, float* __restrict__ sq,
    __bf16* __restrict__ qf) {
  __shared__ float sacc[16][17];
  const int b = blockIdx.y;
  const int g = blockIdx.x;  // 0..31
  const int tid = threadIdx.x;
  const int kk0 = tid >> 6;
  const int lane = tid & 63;
  const int lr = lane & 15, lg = lane >> 4;
  const float* row = q + ((size_t)(b * kI + g * 16 + lr)) * kD;
  float sp = 0.f;
#pragma unroll
  for (int kk = kk0; kk < 16; kk += 4) {
    const int ka = kk * 32 + lg * 8;
    f32x4 v0 = *(const f32x4*)(row + ka);
    f32x4 v1 = *(const f32x4*)(row + ka + 4);
    f32x4 u0 = *(const f32x4*)(w_q + ka);
    f32x4 u1 = *(const f32x4*)(w_q + ka + 4);
    sp += dot8(v0, v1, u0, u1);
    bf16x8 o = {(__bf16)v0.x, (__bf16)v0.y, (__bf16)v0.z, (__bf16)v0.w,
                (__bf16)v1.x, (__bf16)v1.y, (__bf16)v1.z, (__bf16)v1.w};
    *(bf16x8*)(qf + ((((size_t)(b * 32 + g)) * 16 + kk) << 9) + lane * 8) = o;
  }
  sacc[lr][kk0 * 4 + lg] = sp;
  __syncthreads();
  if (tid < 16) {
    float s = 0.f;
#pragma unroll
    for (int j = 0; j < 16; ++j) s += sacc[tid][j];
    sq[b * kI + g * 16 + tid] = s + b_q[0];
  }
}

// vf[((b*32+gd)*16+kki)*512 + lane*8 + j] = bf16(q[b][kki*32+(lane>>4)*8+j]
//                                                 [gd*16+(lane&15)])
__global__ __launch_bounds__(256) void prep_vf_kernel(
    const float* __restrict__ q, __bf16* __restrict__ vf) {
  __shared__ float ts[64][68];
  const int b = blockIdx.z;
  const int i0 = blockIdx.x * 64;
  const int d0 = blockIdx.y * 64;
  const int tid = threadIdx.x;
  const int r = tid >> 2;
  const int cg = (tid & 3) * 16;
#pragma unroll
  for (int j = 0; j < 4; ++j) {
    f32x4 v = *(const f32x4*)(q + ((size_t)(b * kI + i0 + r)) * kD + d0 + cg + 4 * j);
    ts[r][cg + 4 * j + 0] = v.x;
    ts[r][cg + 4 * j + 1] = v.y;
    ts[r][cg + 4 * j + 2] = v.z;
    ts[r][cg + 4 * j + 3] = v.w;
  }
  __syncthreads();
  const int dl = tid >> 2;
  const int ig = (tid & 3) * 16;
  bf16x8 o0, o1;
#pragma unroll
  for (int j = 0; j < 8; ++j) o0[j] = (__bf16)ts[ig + j][dl];
#pragma unroll
  for (int j = 0; j < 8; ++j) o1[j] = (__bf16)ts[ig + 8 + j][dl];
  const int gd = (d0 >> 4) + (dl >> 4);
  const int lr = dl & 15;
  const int kki0 = (i0 >> 5) + (ig >> 5);
  const int lg0 = (ig & 31) >> 3;
  const int i1 = ig + 8;
  const int kki1 = (i0 >> 5) + (i1 >> 5);
  const int lg1 = (i1 & 31) >> 3;
  *(bf16x8*)(vf + ((((size_t)(b * 32 + gd)) * 16 + kki0) << 9) +
             (lg0 * 16 + lr) * 8) = o0;
  *(bf16x8*)(vf + ((((size_t)(b * 32 + gd)) * 16 + kki1) << 9) +
             (lg1 * 16 + lr) * 8) = o1;
}

__global__ __launch_bounds__(512, 4) void fused_attn(
    const float* __restrict__ c, const __bf16* __restrict__ qf,
    const __bf16* __restrict__ vf, const float* __restrict__ w_cq,
    const float* __restrict__ w_c, const float* __restrict__ b_c,
    const float* __restrict__ b_cq, const float* __restrict__ sq,
    float* __restrict__ out, float* __restrict__ mrow) {
  // lAP: 16 k-chunks x 32 rows x 72B. Holds A (phase 1), then P (phase 2).
  __shared__ __align__(16) char lAP[16 * 2304];
  __shared__ float scrow[32];
  __shared__ float redm[256];
  __shared__ float reds[256];

  const int b = blockIdx.y;
  const int t0 = blockIdx.x * 32;
  const int tid = threadIdx.x;
  const int w = tid >> 6;  // 0..7: 64-wide i (phase1) / d (phase2) slice
  const int lane = tid & 63;
  const int lr = lane & 15, lg = lane >> 4;

  // ---- stage A = bf16(c .* w_cq) -> lAP (k-chunked); sc rowdot folded ----
  {
    const int srow = tid >> 4;       // 0..31
    const int col4 = (tid & 15) * 4; // 0..60
    const float* crow = c + ((size_t)(b * kT + t0 + srow)) * kD;
    float scp = 0.f;
#pragma unroll
    for (int j = 0; j < 8; ++j) {
      const int col = col4 + j * 64;
      f32x4 v = *(const f32x4*)(crow + col);
      const f32x4 wq = *(const f32x4*)(w_cq + col);
      const f32x4 wc = *(const f32x4*)(w_c + col);
      scp += v.x * wc.x + v.y * wc.y + v.z * wc.z + v.w * wc.w;
      v *= wq;
      bf16x4 bv = {(__bf16)v.x, (__bf16)v.y, (__bf16)v.z, (__bf16)v.w};
      *(bf16x4*)(lAP + (col >> 5) * 2304 + srow * 72 + (col & 31) * 2) = bv;
    }
    scp += __shfl_xor(scp, 1, 64);
    scp += __shfl_xor(scp, 2, 64);
    scp += __shfl_xor(scp, 4, 64);
    scp += __shfl_xor(scp, 8, 64);
    if ((tid & 15) == 0) scrow[srow] = scp + b_c[0];
  }
  __syncthreads();

  // ---------------- Phase 1: S = A @ qf (LDS A, prefetched B) ------------
  const __bf16* qfb = qf + (((size_t)(b * 32 + w * 4)) * 16 << 9) + lane * 8;
  f32x4 acc[2][4] = {};
  bf16x8 bcur[4], bnxt[4];
#pragma unroll
  for (int n4 = 0; n4 < 4; ++n4)
    bcur[n4] = *(const bf16x8*)(qfb + (((size_t)(n4 * 16)) << 9));
#pragma unroll
  for (int kk = 0; kk < 16; ++kk) {
    if (kk < 15) {
#pragma unroll
      for (int n4 = 0; n4 < 4; ++n4)
        bnxt[n4] = *(const bf16x8*)(qfb + (((size_t)(n4 * 16 + kk + 1)) << 9));
    }
    const bf16x8 a0 = *(const bf16x8*)(lAP + kk * 2304 + lr * 72 + lg * 16);
    const bf16x8 a1 = *(const bf16x8*)(lAP + kk * 2304 + (16 + lr) * 72 + lg * 16);
#pragma unroll
    for (int n4 = 0; n4 < 4; ++n4) {
      acc[0][n4] = __builtin_amdgcn_mfma_f32_16x16x32_bf16(a0, bcur[n4], acc[0][n4], 0, 0, 0);
      acc[1][n4] = __builtin_amdgcn_mfma_f32_16x16x32_bf16(a1, bcur[n4], acc[1][n4], 0, 0, 0);
    }
#pragma unroll
    for (int n4 = 0; n4 < 4; ++n4) bcur[n4] = bnxt[n4];
  }

  // biases
  const float bq = b_cq[0];
  float sqv[4];
#pragma unroll
  for (int n4 = 0; n4 < 4; ++n4) sqv[n4] = sq[b * kI + w * 64 + n4 * 16 + lr];
  float scr[2][4];
#pragma unroll
  for (int m = 0; m < 2; ++m)
#pragma unroll
    for (int r = 0; r < 4; ++r) scr[m][r] = scrow[m * 16 + lg * 4 + r] + bq;
#pragma unroll
  for (int m = 0; m < 2; ++m)
#pragma unroll
    for (int n4 = 0; n4 < 4; ++n4)
#pragma unroll
      for (int r = 0; r < 4; ++r) acc[m][n4][r] += scr[m][r] + sqv[n4];

  // ---------------- exact softmax over i (512) ---------------------------
  float mx[2][4];
#pragma unroll
  for (int m = 0; m < 2; ++m)
#pragma unroll
    for (int r = 0; r < 4; ++r) {
      float v = acc[m][0][r];
#pragma unroll
      for (int n4 = 1; n4 < 4; ++n4) v = fmaxf(v, acc[m][n4][r]);
#pragma unroll
      for (int off = 1; off <= 8; off <<= 1) v = fmaxf(v, __shfl_xor(v, off, 64));
      mx[m][r] = v;
    }
  if (lr == 0) {
#pragma unroll
    for (int m = 0; m < 2; ++m)
#pragma unroll
      for (int r = 0; r < 4; ++r)
        redm[w * 32 + m * 16 + lg * 4 + r] = mx[m][r];
  }
  __syncthreads();
#pragma unroll
  for (int m = 0; m < 2; ++m)
#pragma unroll
    for (int r = 0; r < 4; ++r) {
      const int rw = m * 16 + lg * 4 + r;
      float v = redm[rw];
#pragma unroll
      for (int w2 = 1; w2 < 8; ++w2) v = fmaxf(v, redm[w2 * 32 + rw]);
      mx[m][r] = v;
    }
  if (w == 0 && lr == 0) {
#pragma unroll
    for (int m = 0; m < 2; ++m)
#pragma unroll
      for (int r = 0; r < 4; ++r)
        mrow[b * kT + t0 + m * 16 + lg * 4 + r] = mx[m][r];
  }

  float sm[2][4] = {};
#pragma unroll
  for (int m = 0; m < 2; ++m)
#pragma unroll
    for (int n4 = 0; n4 < 4; ++n4)
#pragma unroll
      for (int r = 0; r < 4; ++r) {
        const float p = __expf(acc[m][n4][r] - mx[m][r]);
        acc[m][n4][r] = p;
        sm[m][r] += p;
      }
#pragma unroll
  for (int m = 0; m < 2; ++m)
#pragma unroll
    for (int r = 0; r < 4; ++r)
#pragma unroll
      for (int off = 1; off <= 8; off <<= 1)
        sm[m][r] += __shfl_xor(sm[m][r], off, 64);
  if (lr == 0) {
#pragma unroll
    for (int m = 0; m < 2; ++m)
#pragma unroll
      for (int r = 0; r < 4; ++r)
        reds[w * 32 + m * 16 + lg * 4 + r] = sm[m][r];
  }
  __syncthreads();
  float inv[2][4];
#pragma unroll
  for (int m = 0; m < 2; ++m)
#pragma unroll
    for (int r = 0; r < 4; ++r) {
      const int rw = m * 16 + lg * 4 + r;
      float v = reds[rw];
#pragma unroll
      for (int w2 = 1; w2 < 8; ++w2) v += reds[w2 * 32 + rw];
      inv[m][r] = 1.f / v;
    }

  // -------- prefetch phase-2 first B frags (overlap with P publish) ------
  const __bf16* vfb = vf + (((size_t)(b * 32 + w * 4)) * 16 << 9) + lane * 8;
  bf16x8 vcur[4], vnxt[4];
#pragma unroll
  for (int n4 = 0; n4 < 4; ++n4)
    vcur[n4] = *(const bf16x8*)(vfb + (((size_t)(n4 * 16)) << 9));

  // ---------------- P (bf16) -> lAP (aliases A), k-chunked ---------------
#pragma unroll
  for (int m = 0; m < 2; ++m)
#pragma unroll
    for (int r = 0; r < 4; ++r) {
      const int trow = m * 16 + lg * 4 + r;
#pragma unroll
      for (int n4 = 0; n4 < 4; ++n4) {
        const int icol = w * 64 + n4 * 16 + lr;
        const int kkc = icol >> 5, kc = icol & 31;
        *(__bf16*)(lAP + kkc * 2304 + trow * 72 + kc * 2) =
            (__bf16)(acc[m][n4][r] * inv[m][r]);
      }
    }
  __syncthreads();

  // ---------------- Phase 2: O = P @ vf (LDS A, prefetched B) ------------
  f32x4 o[2][4] = {};
#pragma unroll
  for (int kki = 0; kki < 16; ++kki) {
    if (kki < 15) {
#pragma unroll
      for (int n4 = 0; n4 < 4; ++n4)
        vnxt[n4] = *(const bf16x8*)(vfb + (((size_t)(n4 * 16 + kki + 1)) << 9));
    }
    const bf16x8 a0 = *(const bf16x8*)(lAP + kki * 2304 + lr * 72 + lg * 16);
    const bf16x8 a1 = *(const bf16x8*)(lAP + kki * 2304 + (16 + lr) * 72 + lg * 16);
#pragma unroll
    for (int n4 = 0; n4 < 4; ++n4) {
      o[0][n4] = __builtin_amdgcn_mfma_f32_16x16x32_bf16(a0, vcur[n4], o[0][n4], 0, 0, 0);
      o[1][n4] = __builtin_amdgcn_mfma_f32_16x16x32_bf16(a1, vcur[n4], o[1][n4], 0, 0, 0);
    }
#pragma unroll
    for (int n4 = 0; n4 < 4; ++n4) vcur[n4] = vnxt[n4];
  }

  // ---------------- epilogue: slots [c | c2q | c*c2q] --------------------
#pragma unroll
  for (int m = 0; m < 2; ++m)
#pragma unroll
    for (int r = 0; r < 4; ++r) {
      const int t = t0 + m * 16 + lg * 4 + r;
      const size_t rb = (size_t)(b * kT + t);
      const float* crow = c + rb * kD;
      float* orow = out + rb * kW;
#pragma unroll
      for (int n4 = 0; n4 < 4; ++n4) {
        const int d = w * 64 + n4 * 16 + lr;
        const float cvv = crow[d];
        const float pv = o[m][n4][r];
        orow[d] = cvv;
        orow[kD + d] = pv;
        orow[2 * kD + d] = cvv * pv;
      }
    }
}

__global__ __launch_bounds__(1024) void t_softmax_kernel(
    const float* __restrict__ mrow, float* __restrict__ bw) {
  const int b = blockIdx.x;
  const int tid = threadIdx.x;
  const float v0 = mrow[b * kT + tid], v1 = mrow[b * kT + tid + 1024];
  __shared__ float redm[16];
  __shared__ float reds[16];
  const int wave = tid >> 6, lane = tid & 63;
  float mx = wave_max(fmaxf(v0, v1));
  if (lane == 0) redm[wave] = mx;
  __syncthreads();
  mx = redm[0];
#pragma unroll
  for (int i = 1; i < 16; ++i) mx = fmaxf(mx, redm[i]);
  const float e0 = __expf(v0 - mx), e1 = __expf(v1 - mx);
  float sm = wave_sum(e0 + e1);
  if (lane == 0) reds[wave] = sm;
  __syncthreads();
  sm = 0.f;
#pragma unroll
  for (int i = 0; i < 16; ++i) sm += reds[i];
  const float inv = 1.f / sm;
  bw[b * kT + tid] = e0 * inv;
  bw[b * kT + tid + 1024] = e1 * inv;
}

__global__ __launch_bounds__(256) void q2c_part_kernel(
    const float* __restrict__ c, const float* __restrict__ bw,
    float* __restrict__ part) {
  const int b = blockIdx.y;
  const int sp = blockIdx.x;
  const int tid = threadIdx.x;
  const int d0 = tid, d1 = tid + 256;
  float a0 = 0.f, a1 = 0.f;
  const int tbase = sp * kTchunk;
  for (int t = 0; t < kTchunk; ++t) {
    const float w = bw[b * kT + tbase + t];
    const float* crow = c + ((size_t)b * kT + tbase + t) * kD;
    a0 += w * crow[d0];
    a1 += w * crow[d1];
  }
  part[((size_t)b * kSplit + sp) * kD + d0] = a0;
  part[((size_t)b * kSplit + sp) * kD + d1] = a1;
}

__global__ __launch_bounds__(512) void q2c_reduce_kernel(
    const float* __restrict__ part, float* __restrict__ q2c) {
  const int b = blockIdx.x;
  const int d = threadIdx.x;
  float s = 0.f;
#pragma unroll
  for (int p = 0; p < kSplit; ++p) s += part[((size_t)b * kSplit + p) * kD + d];
  q2c[b * kD + d] = s;
}

__global__ __launch_bounds__(128) void slot3_kernel(
    const float* __restrict__ c, const float* __restrict__ q2c,
    float* __restrict__ out) {
  const int row = blockIdx.x;  // b*kT + t
  const int b = row >> 11;
  const int x4 = threadIdx.x * 4;
  f32x4 cv = *(const f32x4*)(c + (size_t)row * kD + x4);
  f32x4 qc = *(const f32x4*)(q2c + b * kD + x4);
  *(f32x4*)(out + (size_t)row * kW + 3 * kD + x4) = cv * qc;
}

extern "C" void kernel_launch(void* const* d_in, const int* in_sizes, int n_in,
                              void* d_out, int out_size, void* d_ws, size_t ws_size,
                              hipStream_t stream) {
  const float* c    = (const float*)d_in[0];
  const float* q    = (const float*)d_in[1];
  const float* w_c  = (const float*)d_in[2];
  const float* b_c  = (const float*)d_in[3];
  const float* w_q  = (const float*)d_in[4];
  const float* b_q  = (const float*)d_in[5];
  const float* w_cq = (const float*)d_in[6];
  const float* b_cq = (const float*)d_in[7];
  float* out = (float*)d_out;
  float* ws = (float*)d_ws;

  // ws layout (floats): sq 4096 | mrow 16384 | bw 16384 | part 131072 |
  //                     q2c 4096; then bf16: qf 2M | vf 2M  (~8.7 MB)
  float* sq   = ws;
  float* mrow = sq + kB * kI;
  float* bw   = mrow + kB * kT;
  float* part = bw + kB * kT;
  float* q2c  = part + (size_t)kB * kSplit * kD;
  __bf16* qf = (__bf16*)(q2c + kB * kD);
  __bf16* vf = qf + (size_t)kB * kI * kD;

  dim3 gpq(kI / 16, kB);
  prep_qf_kernel<<<gpq, 256, 0, stream>>>(q, w_q, b_q, sq, qf);
  dim3 gpv(kI / 64, kD / 64, kB);
  prep_vf_kernel<<<gpv, 256, 0, stream>>>(q, vf);

  dim3 gf(kT / 32, kB);
  fused_attn<<<gf, 512, 0, stream>>>(c, qf, vf, w_cq, w_c, b_c, b_cq, sq, out,
                                     mrow);

  t_softmax_kernel<<<kB, 1024, 0, stream>>>(mrow, bw);
  dim3 gq(kSplit, kB);
  q2c_part_kernel<<<gq, 256, 0, stream>>>(c, bw, part);
  q2c_reduce_kernel<<<kB, 512, 0, stream>>>(part, q2c);

  slot3_kernel<<<kB * kT, 128, 0, stream>>>(c, q2c, out);
}